// Round 9
// baseline (319.636 us; speedup 1.0000x reference)
//
#include <hip/hip_runtime.h>
#include <hip/hip_fp16.h>

#define FD 128

typedef __attribute__((ext_vector_type(8))) short bf16x8;
typedef __attribute__((ext_vector_type(4))) float f32x4;

__device__ __forceinline__ float lrelu(float x, float s){ return x > 0.f ? x : s*x; }

__device__ __forceinline__ unsigned short f2bf(float f){
  unsigned u = __builtin_bit_cast(unsigned, f);
  return (unsigned short)((u + 0x7FFFu + ((u >> 16) & 1u)) >> 16);
}
__device__ __forceinline__ float bf2f(unsigned short h){
  unsigned u = ((unsigned)h) << 16;
  return __builtin_bit_cast(float, u);
}

// WT storage (per layer): single ushort buffer, 36864 entries = 73728 B.
//   [0, 18432)     : hi part, XOR-swizzled row-major [144][128]
//   [18432, 36864) : lo part, same layout
// swizzled index for (row w, k): si = w*128 + (k ^ ((w&7)<<3))

// ---------------- count (XCD-partitioned) + wprep fused ----------------
__global__ __launch_bounds__(256) void count_wprep_kernel(const int* __restrict__ dst,
    int* __restrict__ counts, int E, unsigned rscale, int nchunk, int nbc,
    const float* __restrict__ W1, const float* __restrict__ W2,
    const float* __restrict__ aS1, const float* __restrict__ aD1,
    const float* __restrict__ aS2, const float* __restrict__ aD2,
    unsigned short* __restrict__ WT1, unsigned short* __restrict__ WT2)
{
  int b = blockIdx.x;
  if (b < nbc){
    int xcd = b & 7, chunk = b >> 3;
    int nv = E >> 2;
    for (int v = chunk*256 + threadIdx.x; v < nv; v += nchunk*256){
      int4 d4 = ((const int4*)dst)[v];
      #pragma unroll
      for (int t = 0; t < 4; ++t){
        int d = (&d4.x)[t];
        unsigned r = (unsigned)(((unsigned long long)(unsigned)d * rscale) >> 32);
        if ((int)r == xcd) atomicAdd(&counts[d], 1);
      }
    }
    if (chunk == 0 && threadIdx.x < (E & 3)){
      int i = (E & ~3) + threadIdx.x;
      int d = dst[i];
      unsigned r = (unsigned)(((unsigned long long)(unsigned)d * rscale) >> 32);
      if ((int)r == xcd) atomicAdd(&counts[d], 1);
    }
    return;
  }
  int id = (b - nbc)*256 + threadIdx.x;
  if (id < 32768){
    const float* W = (id < 16384) ? W1 : W2;
    unsigned short* T = (id < 16384) ? WT1 : WT2;
    int idx = id & 16383;
    int k = idx >> 7, c = idx & 127;
    int w = ((c & 7) << 4) | (c >> 3);   // channel c -> row w (thread (ct,r) -> ch r*8+ct)
    int si = w*128 + (k ^ ((w & 7) << 3));
    float v = W[idx];
    unsigned short h = f2bf(v);
    T[si] = h;
    T[18432 + si] = f2bf(v - bf2f(h));
  } else if (id < 34816){
    int id2 = id - 32768;
    int layer = id2 >> 10;
    int id3 = id2 & 1023;
    int k = id3 >> 3, cc = id3 & 7;
    const float* W  = layer ? W2 : W1;
    const float* av = (cc < 4) ? (layer ? aS2 : aS1) : (layer ? aD2 : aD1);
    unsigned short* T = layer ? WT2 : WT1;
    int h = cc & 3, base = h*32;
    float acc = 0.f;
    #pragma unroll 8
    for (int c = 0; c < 32; ++c) acc += W[k*FD + base + c] * av[base + c];
    int w = 128 + cc;
    int si = w*128 + (k ^ ((w & 7) << 3));
    unsigned short hh = f2bf(acc);
    T[si] = hh;
    T[18432 + si] = f2bf(acc - bf2f(hh));
  } else if (id < 36864){
    int id2 = id - 34816;
    int layer = id2 >> 10;
    int id3 = id2 & 1023;
    int w = 136 + (id3 >> 7), k = id3 & 127;
    unsigned short* T = layer ? WT2 : WT1;
    int si = w*128 + (k ^ ((w & 7) << 3));
    T[si] = 0;
    T[18432 + si] = 0;
  }
}

// ---------------- multi-block scan of (counts[i]+1), 3 phases ----------------
__global__ __launch_bounds__(512) void scan1_kernel(const int* __restrict__ counts,
    int* __restrict__ offsets, int* __restrict__ blocksum, int n){
  __shared__ int wsum[8];
  int tid = threadIdx.x, lane = tid & 63, wv = tid >> 6;
  int i = blockIdx.x*512 + tid;
  int v = (i < n) ? counts[i] + 1 : 0;
  int incl = v;
  #pragma unroll
  for (int off = 1; off < 64; off <<= 1){
    int t = __shfl_up(incl, off);
    if (lane >= off) incl += t;
  }
  if (lane == 63) wsum[wv] = incl;
  __syncthreads();
  if (wv == 0 && lane < 8){
    int s = wsum[lane];
    #pragma unroll
    for (int off = 1; off < 8; off <<= 1){
      int t = __shfl_up(s, off);
      if (lane >= off) s += t;
    }
    wsum[lane] = s;
  }
  __syncthreads();
  int woff = (wv > 0) ? wsum[wv-1] : 0;
  incl += woff;
  if (i < n) offsets[i] = incl;          // local inclusive
  if (tid == 511) blocksum[blockIdx.x] = incl;
}

__global__ __launch_bounds__(64) void scan2_kernel(int* __restrict__ blocksum,
    int* __restrict__ offsets, int nb, int n){
  int lane = threadIdx.x;
  int i0 = 2*lane, i1 = 2*lane + 1;
  int v0 = (i0 < nb) ? blocksum[i0] : 0;
  int v1 = (i1 < nb) ? blocksum[i1] : 0;
  int pair = v0 + v1;
  int incl = pair;
  #pragma unroll
  for (int off = 1; off < 64; off <<= 1){
    int t = __shfl_up(incl, off);
    if (lane >= off) incl += t;
  }
  int excl = incl - pair;
  if (i0 < nb) blocksum[i0] = excl;
  if (i1 < nb) blocksum[i1] = excl + v0;
  if (lane == 63) offsets[n] = incl;
}

__global__ __launch_bounds__(512) void scan3_kernel(const int* __restrict__ counts,
    int* __restrict__ offsets, const int* __restrict__ blocksum,
    int* __restrict__ csr, int n){
  int i = blockIdx.x*512 + threadIdx.x;
  if (i >= n) return;
  int v = counts[i] + 1;
  int gl = offsets[i] + blocksum[blockIdx.x];
  offsets[i] = gl - v;
  csr[gl - 1] = i;
}

// ---------------- fill (XCD-partitioned; slots 0..deg-1) ----------------
__global__ __launch_bounds__(256) void fill_part_kernel(const int* __restrict__ ei,
    const int* __restrict__ offsets, int* __restrict__ counts, int* __restrict__ csr,
    int E, unsigned rscale, int nchunk){
  int b = blockIdx.x;
  int xcd = b & 7, chunk = b >> 3;
  int nv = E >> 2;
  for (int v = chunk*256 + threadIdx.x; v < nv; v += nchunk*256){
    int4 s4 = ((const int4*)ei)[v];
    int4 d4 = ((const int4*)(ei + E))[v];
    #pragma unroll
    for (int t = 0; t < 4; ++t){
      int d = (&d4.x)[t];
      unsigned r = (unsigned)(((unsigned long long)(unsigned)d * rscale) >> 32);
      if ((int)r == xcd){
        int c = atomicSub(&counts[d], 1) - 1;
        csr[offsets[d] + c] = (&s4.x)[t];
      }
    }
  }
  if (chunk == 0 && threadIdx.x < (E & 3)){
    int i = (E & ~3) + threadIdx.x;
    int d = ei[E + i];
    unsigned r = (unsigned)(((unsigned long long)(unsigned)d * rscale) >> 32);
    if ((int)r == xcd){
      int c = atomicSub(&counts[d], 1) - 1;
      csr[offsets[d] + c] = ei[i];
    }
  }
}

// ---------------- MFMA GEMM: [H(fp16, packed) | attS | attD] ----------------
template<int SPLITIN>
__global__ __launch_bounds__(256) void gemm_mfma_kernel(
    const float* __restrict__ Xf,
    const unsigned short* __restrict__ Xh, const unsigned short* __restrict__ Xl,
    const unsigned short* __restrict__ WT,
    uint4* __restrict__ H16, float* __restrict__ attS, float* __restrict__ attD, int n)
{
  __shared__ unsigned short smem[36864];     // 73728 B: [hi 18432][lo 18432]
  int tid = threadIdx.x;
  int wv = tid >> 6, lane = tid & 63;
  int g = lane >> 4, r = lane & 15;
  int rbase = blockIdx.x*64 + wv*16;
  int arow = rbase + r; if (arow >= n) arow = n - 1;

  {
    const uint4* src = (const uint4*)WT;
    uint4* dst = (uint4*)smem;
    #pragma unroll
    for (int i = 0; i < 18; ++i) dst[tid + i*256] = src[tid + i*256];
  }

  bf16x8 Ah[4], Al[4];
  if (SPLITIN){
    const bf16x8* ph = (const bf16x8*)(Xh + (size_t)arow*FD);
    const bf16x8* pl = (const bf16x8*)(Xl + (size_t)arow*FD);
    #pragma unroll
    for (int kc = 0; kc < 4; ++kc){ Ah[kc] = ph[kc*4 + g]; Al[kc] = pl[kc*4 + g]; }
  } else {
    const float4* px = (const float4*)(Xf + (size_t)arow*FD);
    #pragma unroll
    for (int kc = 0; kc < 4; ++kc){
      float4 x0 = px[(kc*4 + g)*2];
      float4 x1 = px[(kc*4 + g)*2 + 1];
      float xs[8] = {x0.x,x0.y,x0.z,x0.w,x1.x,x1.y,x1.z,x1.w};
      #pragma unroll
      for (int t = 0; t < 8; ++t){
        unsigned short hh = f2bf(xs[t]);
        Ah[kc][t] = (short)hh;
        Al[kc][t] = (short)f2bf(xs[t] - bf2f(hh));
      }
    }
  }

  __syncthreads();

  f32x4 acc[9];
  #pragma unroll
  for (int ct = 0; ct < 9; ++ct) acc[ct] = (f32x4){0.f,0.f,0.f,0.f};

  #pragma unroll
  for (int ct = 0; ct < 9; ++ct){
    int wrow = ct*16 + r;
    int sw = (wrow & 7) << 3;
    #pragma unroll
    for (int kc = 0; kc < 4; ++kc){
      int kidx = (kc*32 + g*8) ^ sw;
      bf16x8 Bh = *(const bf16x8*)&smem[wrow*128 + kidx];
      bf16x8 Bl = *(const bf16x8*)&smem[18432 + wrow*128 + kidx];
      acc[ct] = __builtin_amdgcn_mfma_f32_16x16x32_bf16(Ah[kc], Bh, acc[ct], 0, 0, 0);
      acc[ct] = __builtin_amdgcn_mfma_f32_16x16x32_bf16(Ah[kc], Bl, acc[ct], 0, 0, 0);
      acc[ct] = __builtin_amdgcn_mfma_f32_16x16x32_bf16(Al[kc], Bh, acc[ct], 0, 0, 0);
    }
  }

  #pragma unroll
  for (int j = 0; j < 4; ++j){
    int row = rbase + g*4 + j;
    if (row < n){
      __half2 p0 = __float22half2_rn(make_float2(acc[0][j], acc[1][j]));
      __half2 p1 = __float22half2_rn(make_float2(acc[2][j], acc[3][j]));
      __half2 p2 = __float22half2_rn(make_float2(acc[4][j], acc[5][j]));
      __half2 p3 = __float22half2_rn(make_float2(acc[6][j], acc[7][j]));
      uint4 pk;
      pk.x = __builtin_bit_cast(unsigned, p0);
      pk.y = __builtin_bit_cast(unsigned, p1);
      pk.z = __builtin_bit_cast(unsigned, p2);
      pk.w = __builtin_bit_cast(unsigned, p3);
      H16[(size_t)row*16 + r] = pk;
      if (r < 4)      attS[row*4 + r]       = acc[8][j];
      else if (r < 8) attD[row*4 + (r - 4)] = acc[8][j];
    }
  }
}

// ---------------- channel-pass softmax + aggregate ----------------
// pass Q = blockIdx.x / bpp handles channels [32Q, 32Q+32) == head Q exactly.
// Per-pass gather slice = n rows x 64 B (3.2 MB) -> fits one XCD's 4 MB L2;
// pass-major dispatch order gives temporal phase separation.
// Per wave (1 dst): p-phase computes p_Q (1 exp) for 64 edges, stride-2 LDS stash;
// gather: 16 groups x 4 lanes, 1 uint4 (8 ch) per lane per edge; reduce via
// shfl_xor 4/8/16/32; epilogue lanes 0-3.
// OUT=0: write bf16 hi/lo quarter rows. OUT=1: partial FC dot -> outstage[wid*4+Q].
template<int OUT>
__global__ __launch_bounds__(256) void agg_pass_kernel(
    const uint4* __restrict__ H16, const float* __restrict__ attS, const float* __restrict__ attD,
    const int* __restrict__ csr, const int* __restrict__ offsets,
    const float* __restrict__ bias, const float* __restrict__ wfc,
    uint4* __restrict__ oh, uint4* __restrict__ ol,
    float* __restrict__ outstage, int n, int bpp)
{
  __shared__ float lds[4][128];
  int pass = blockIdx.x / bpp;
  int bin  = blockIdx.x - pass*bpp;
  int wid  = bin*4 + (threadIdx.x >> 6);
  int lane = threadIdx.x & 63;
  if (wid >= n) return;
  int q = lane & 3, grp = lane >> 2;
  float* wl = lds[threadIdx.x >> 6];
  int* wli = (int*)wl;

  int start = offsets[wid], end = offsets[wid+1];
  float adQ = attD[wid*4 + pass];

  float z = 0.f;
  float acc[8];
  #pragma unroll
  for (int k = 0; k < 8; ++k) acc[k] = 0.f;

  for (int base2 = start; base2 < end; base2 += 64){
    int cnt = end - base2; if (cnt > 64) cnt = 64;
    float p = 0.f; int sb = 0;
    if (lane < cnt){
      int s = csr[base2 + lane];
      sb = (s << 4) + (pass << 2);            // uint4 index of this row's quarter
      p = __expf(lrelu(attS[s*4 + pass] + adQ, 0.2f));
    }
    z += p;
    wli[lane*2]  = sb;
    wl[lane*2+1] = p;
    asm volatile("s_waitcnt lgkmcnt(0)" ::: "memory");
    __builtin_amdgcn_sched_barrier(0);
    for (int jj = grp; jj < cnt; jj += 16){
      int sbj  = wli[jj*2];
      float pj = wl[jj*2+1];
      uint4 u = H16[(unsigned)(sbj + q)];
      float2 t0 = __half22float2(__builtin_bit_cast(__half2, u.x));
      float2 t1 = __half22float2(__builtin_bit_cast(__half2, u.y));
      float2 t2 = __half22float2(__builtin_bit_cast(__half2, u.z));
      float2 t3 = __half22float2(__builtin_bit_cast(__half2, u.w));
      acc[0] += pj*t0.x; acc[1] += pj*t0.y;
      acc[2] += pj*t1.x; acc[3] += pj*t1.y;
      acc[4] += pj*t2.x; acc[5] += pj*t2.y;
      acc[6] += pj*t3.x; acc[7] += pj*t3.y;
    }
    __builtin_amdgcn_sched_barrier(0);
  }

  #pragma unroll
  for (int off = 32; off >= 1; off >>= 1) z += __shfl_xor(z, off);
  #pragma unroll
  for (int k = 0; k < 8; ++k){
    acc[k] += __shfl_xor(acc[k], 4);
    acc[k] += __shfl_xor(acc[k], 8);
    acc[k] += __shfl_xor(acc[k], 16);
    acc[k] += __shfl_xor(acc[k], 32);
  }

  if (lane < 4){
    float inv = 1.f / (z + 1e-16f);
    int ch0 = (pass << 5) + (lane << 3);
    const float4* b4 = (const float4*)bias;
    float4 b0 = b4[ch0 >> 2], b1 = b4[(ch0 >> 2) + 1];
    float o[8];
    o[0]=lrelu(acc[0]*inv+b0.x,0.01f); o[1]=lrelu(acc[1]*inv+b0.y,0.01f);
    o[2]=lrelu(acc[2]*inv+b0.z,0.01f); o[3]=lrelu(acc[3]*inv+b0.w,0.01f);
    o[4]=lrelu(acc[4]*inv+b1.x,0.01f); o[5]=lrelu(acc[5]*inv+b1.y,0.01f);
    o[6]=lrelu(acc[6]*inv+b1.z,0.01f); o[7]=lrelu(acc[7]*inv+b1.w,0.01f);
    if (OUT){
      const float4* w4 = (const float4*)wfc;
      float4 w0 = w4[ch0 >> 2], w1 = w4[(ch0 >> 2) + 1];
      float t = o[0]*w0.x + o[1]*w0.y + o[2]*w0.z + o[3]*w0.w
              + o[4]*w1.x + o[5]*w1.y + o[6]*w1.z + o[7]*w1.w;
      t += __shfl_xor(t, 1);
      t += __shfl_xor(t, 2);
      if (lane == 0) outstage[wid*4 + pass] = t;
    } else {
      unsigned hh[8], ll[8];
      #pragma unroll
      for (int i = 0; i < 8; ++i){
        unsigned short h = f2bf(o[i]);
        hh[i] = h; ll[i] = f2bf(o[i] - bf2f(h));
      }
      uint4 ph = {hh[0]|(hh[1]<<16), hh[2]|(hh[3]<<16), hh[4]|(hh[5]<<16), hh[6]|(hh[7]<<16)};
      uint4 pl = {ll[0]|(ll[1]<<16), ll[2]|(ll[3]<<16), ll[4]|(ll[5]<<16), ll[6]|(ll[7]<<16)};
      int oi = wid*16 + (pass << 2) + lane;
      oh[oi] = ph;
      ol[oi] = pl;
    }
  }
}

// final FC sum: out[i] = sum of 4 per-pass partials + bfc.
__global__ __launch_bounds__(256) void fcsum_kernel(const float4* __restrict__ outstage,
    const float* __restrict__ bfc, float* __restrict__ out, int n){
  int i = blockIdx.x*256 + threadIdx.x;
  if (i < n){
    float4 v = outstage[i];
    out[i] = v.x + v.y + v.z + v.w + bfc[0];
  }
}

extern "C" void kernel_launch(void* const* d_in, const int* in_sizes, int n_in,
                              void* d_out, int out_size, void* d_ws, size_t ws_size,
                              hipStream_t stream)
{
  const float* x   = (const float*)d_in[0];
  const int*   ei  = (const int*)d_in[1];
  const float* W1  = (const float*)d_in[2];
  const float* aS1 = (const float*)d_in[3];
  const float* aD1 = (const float*)d_in[4];
  const float* b1  = (const float*)d_in[5];
  const float* W2  = (const float*)d_in[6];
  const float* aS2 = (const float*)d_in[7];
  const float* aD2 = (const float*)d_in[8];
  const float* b2  = (const float*)d_in[9];
  const float* Wfc = (const float*)d_in[10];
  const float* bfc = (const float*)d_in[11];
  float* out = (float*)d_out;

  int n = in_sizes[0] / FD;
  int E = in_sizes[1] / 2;
  int etot = E + n;
  unsigned rscale = (unsigned)(((8ULL << 32) + n - 1) / (unsigned long long)n);

  char* p = (char*)d_ws;
  auto alloc = [&](size_t bytes)->void*{
    void* r = (void*)p;
    p += (bytes + 255) & ~(size_t)255;
    return r;
  };
  int* counts    = (int*)alloc((size_t)n * 4);
  int* offsets   = (int*)alloc((size_t)(n + 1) * 4);
  int* blocksum  = (int*)alloc(1024 * 4);
  int* csr       = (int*)alloc((size_t)etot * 4);
  float* attS1   = (float*)alloc((size_t)n * 4 * 4);
  float* attD1   = (float*)alloc((size_t)n * 4 * 4);
  float* attS2   = (float*)alloc((size_t)n * 4 * 4);
  float* attD2   = (float*)alloc((size_t)n * 4 * 4);
  float* outstage= (float*)alloc((size_t)n * 4 * 4);
  unsigned short* WT1 = (unsigned short*)alloc(36864*2);
  unsigned short* WT2 = (unsigned short*)alloc(36864*2);
  uint4* H16     = (uint4*)alloc((size_t)n * FD * 2);
  unsigned short* H2h = (unsigned short*)alloc((size_t)n * FD * 2);
  unsigned short* H2l = (unsigned short*)alloc((size_t)n * FD * 2);

  hipMemsetAsync(counts, 0, (size_t)n * 4, stream);

  const int NB_PART = 512;            // 64 chunks x 8 XCD-filtered block groups
  int nsb = (n + 511) / 512;          // scan blocks (<=128 for n<=65536)
  count_wprep_kernel<<<NB_PART + 144, 256, 0, stream>>>(ei + E, counts, E, rscale,
      NB_PART/8, NB_PART, W1, W2, aS1, aD1, aS2, aD2, WT1, WT2);
  scan1_kernel<<<nsb, 512, 0, stream>>>(counts, offsets, blocksum, n);
  scan2_kernel<<<1, 64, 0, stream>>>(blocksum, offsets, nsb, n);
  scan3_kernel<<<nsb, 512, 0, stream>>>(counts, offsets, blocksum, csr, n);
  fill_part_kernel<<<NB_PART, 256, 0, stream>>>(ei, offsets, counts, csr, E, rscale, NB_PART/8);

  int gb = (n + 63) / 64;
  int bpp = (n + 3) / 4;              // blocks per pass (4 dsts per block)

  // layer 1
  gemm_mfma_kernel<0><<<gb, 256, 0, stream>>>(x, nullptr, nullptr, WT1,
                                              H16, attS1, attD1, n);
  agg_pass_kernel<0><<<4*bpp, 256, 0, stream>>>(H16, attS1, attD1, csr, offsets,
                                b1, nullptr, (uint4*)H2h, (uint4*)H2l, nullptr, n, bpp);
  // layer 2 (+ fused FC via per-pass partials)
  gemm_mfma_kernel<1><<<gb, 256, 0, stream>>>(nullptr, H2h, H2l, WT2,
                                              H16, attS2, attD2, n);
  agg_pass_kernel<1><<<4*bpp, 256, 0, stream>>>(H16, attS2, attD2, csr, offsets,
                                b2, Wfc, nullptr, nullptr, outstage, n, bpp);
  fcsum_kernel<<<(n + 255)/256, 256, 0, stream>>>((const float4*)outstage, bfc, out, n);
}

// Round 10
// 201.341 us; speedup vs baseline: 1.5875x; 1.5875x over previous
//
#include <hip/hip_runtime.h>
#include <hip/hip_fp16.h>

#define FD 128

typedef __attribute__((ext_vector_type(8))) short bf16x8;
typedef __attribute__((ext_vector_type(4))) float f32x4;

__device__ __forceinline__ float lrelu(float x, float s){ return x > 0.f ? x : s*x; }

__device__ __forceinline__ unsigned short f2bf(float f){
  unsigned u = __builtin_bit_cast(unsigned, f);
  return (unsigned short)((u + 0x7FFFu + ((u >> 16) & 1u)) >> 16);
}
__device__ __forceinline__ float bf2f(unsigned short h){
  unsigned u = ((unsigned)h) << 16;
  return __builtin_bit_cast(float, u);
}

// WT storage (per layer): single ushort buffer, 36864 entries = 73728 B.
//   [0, 18432)     : hi part, XOR-swizzled row-major [144][128]
//   [18432, 36864) : lo part, same layout
// swizzled index for (row w, k): si = w*128 + (k ^ ((w&7)<<3))

// ---------------- count (XCD-partitioned) + wprep fused ----------------
__global__ __launch_bounds__(256) void count_wprep_kernel(const int* __restrict__ dst,
    int* __restrict__ counts, int E, unsigned rscale, int nchunk, int nbc,
    const float* __restrict__ W1, const float* __restrict__ W2,
    const float* __restrict__ aS1, const float* __restrict__ aD1,
    const float* __restrict__ aS2, const float* __restrict__ aD2,
    unsigned short* __restrict__ WT1, unsigned short* __restrict__ WT2)
{
  int b = blockIdx.x;
  if (b < nbc){
    int xcd = b & 7, chunk = b >> 3;
    int nv = E >> 2;
    for (int v = chunk*256 + threadIdx.x; v < nv; v += nchunk*256){
      int4 d4 = ((const int4*)dst)[v];
      #pragma unroll
      for (int t = 0; t < 4; ++t){
        int d = (&d4.x)[t];
        unsigned r = (unsigned)(((unsigned long long)(unsigned)d * rscale) >> 32);
        if ((int)r == xcd) atomicAdd(&counts[d], 1);
      }
    }
    if (chunk == 0 && threadIdx.x < (E & 3)){
      int i = (E & ~3) + threadIdx.x;
      int d = dst[i];
      unsigned r = (unsigned)(((unsigned long long)(unsigned)d * rscale) >> 32);
      if ((int)r == xcd) atomicAdd(&counts[d], 1);
    }
    return;
  }
  int id = (b - nbc)*256 + threadIdx.x;
  if (id < 32768){
    const float* W = (id < 16384) ? W1 : W2;
    unsigned short* T = (id < 16384) ? WT1 : WT2;
    int idx = id & 16383;
    int k = idx >> 7, c = idx & 127;
    int w = ((c & 7) << 4) | (c >> 3);   // channel c -> row w (thread (ct,r) -> ch r*8+ct)
    int si = w*128 + (k ^ ((w & 7) << 3));
    float v = W[idx];
    unsigned short h = f2bf(v);
    T[si] = h;
    T[18432 + si] = f2bf(v - bf2f(h));
  } else if (id < 34816){
    int id2 = id - 32768;
    int layer = id2 >> 10;
    int id3 = id2 & 1023;
    int k = id3 >> 3, cc = id3 & 7;
    const float* W  = layer ? W2 : W1;
    const float* av = (cc < 4) ? (layer ? aS2 : aS1) : (layer ? aD2 : aD1);
    unsigned short* T = layer ? WT2 : WT1;
    int h = cc & 3, base = h*32;
    float acc = 0.f;
    #pragma unroll 8
    for (int c = 0; c < 32; ++c) acc += W[k*FD + base + c] * av[base + c];
    int w = 128 + cc;
    int si = w*128 + (k ^ ((w & 7) << 3));
    unsigned short hh = f2bf(acc);
    T[si] = hh;
    T[18432 + si] = f2bf(acc - bf2f(hh));
  } else if (id < 36864){
    int id2 = id - 34816;
    int layer = id2 >> 10;
    int id3 = id2 & 1023;
    int w = 136 + (id3 >> 7), k = id3 & 127;
    unsigned short* T = layer ? WT2 : WT1;
    int si = w*128 + (k ^ ((w & 7) << 3));
    T[si] = 0;
    T[18432 + si] = 0;
  }
}

// ---------------- multi-block scan of (counts[i]+1), 2 phases ----------------
// scan1: per-block inclusive scan -> offsets[i] (local), blocksum[b].
__global__ __launch_bounds__(512) void scan1_kernel(const int* __restrict__ counts,
    int* __restrict__ offsets, int* __restrict__ blocksum, int n){
  __shared__ int wsum[8];
  int tid = threadIdx.x, lane = tid & 63, wv = tid >> 6;
  int i = blockIdx.x*512 + tid;
  int v = (i < n) ? counts[i] + 1 : 0;
  int incl = v;
  #pragma unroll
  for (int off = 1; off < 64; off <<= 1){
    int t = __shfl_up(incl, off);
    if (lane >= off) incl += t;
  }
  if (lane == 63) wsum[wv] = incl;
  __syncthreads();
  if (wv == 0 && lane < 8){
    int s = wsum[lane];
    #pragma unroll
    for (int off = 1; off < 8; off <<= 1){
      int t = __shfl_up(s, off);
      if (lane >= off) s += t;
    }
    wsum[lane] = s;
  }
  __syncthreads();
  int woff = (wv > 0) ? wsum[wv-1] : 0;
  incl += woff;
  if (i < n) offsets[i] = incl;          // local inclusive
  if (tid == 511) blocksum[blockIdx.x] = incl;
}

// scan3: per-block lookback over blocksum (<=128 entries), finalize exclusive
// global offsets + write self-loop csr entries; last element writes offsets[n].
__global__ __launch_bounds__(512) void scan3_kernel(const int* __restrict__ counts,
    int* __restrict__ offsets, const int* __restrict__ blocksum,
    int* __restrict__ csr, int n, int nsb){
  __shared__ int boff_s;
  int tid = threadIdx.x, b = blockIdx.x;
  if (tid < 64){
    int s = 0;
    for (int j = tid; j < b; j += 64) s += blocksum[j];
    #pragma unroll
    for (int off = 32; off >= 1; off >>= 1) s += __shfl_xor(s, off);
    if (tid == 0) boff_s = s;
  }
  __syncthreads();
  int i = b*512 + tid;
  if (i >= n) return;
  int boff = boff_s;
  int v = counts[i] + 1;
  int gl = offsets[i] + boff;
  offsets[i] = gl - v;
  csr[gl - 1] = i;
  if (i == n - 1) offsets[n] = gl;
}

// ---------------- fill (XCD-partitioned; slots 0..deg-1) ----------------
__global__ __launch_bounds__(256) void fill_part_kernel(const int* __restrict__ ei,
    const int* __restrict__ offsets, int* __restrict__ counts, int* __restrict__ csr,
    int E, unsigned rscale, int nchunk){
  int b = blockIdx.x;
  int xcd = b & 7, chunk = b >> 3;
  int nv = E >> 2;
  for (int v = chunk*256 + threadIdx.x; v < nv; v += nchunk*256){
    int4 s4 = ((const int4*)ei)[v];
    int4 d4 = ((const int4*)(ei + E))[v];
    #pragma unroll
    for (int t = 0; t < 4; ++t){
      int d = (&d4.x)[t];
      unsigned r = (unsigned)(((unsigned long long)(unsigned)d * rscale) >> 32);
      if ((int)r == xcd){
        int c = atomicSub(&counts[d], 1) - 1;
        csr[offsets[d] + c] = (&s4.x)[t];
      }
    }
  }
  if (chunk == 0 && threadIdx.x < (E & 3)){
    int i = (E & ~3) + threadIdx.x;
    int d = ei[E + i];
    unsigned r = (unsigned)(((unsigned long long)(unsigned)d * rscale) >> 32);
    if ((int)r == xcd){
      int c = atomicSub(&counts[d], 1) - 1;
      csr[offsets[d] + c] = ei[i];
    }
  }
}

// ---------------- MFMA GEMM: [H(fp16, packed) | attS | attD] ----------------
// B operand (WT) staged in LDS once per block (73.7 KB), shared by 4 waves.
// ds_read_b128 on the XOR-swizzled layout is bank-conflict-free.
// SPLITIN=0: A from f32 (layer 1).  SPLITIN=1: A from packed fp16 (layer 2);
// both convert to bf16 hi/lo in-register.
template<int SPLITIN>
__global__ __launch_bounds__(256) void gemm_mfma_kernel(
    const float* __restrict__ Xf, const unsigned short* __restrict__ X16,
    const unsigned short* __restrict__ WT,
    uint4* __restrict__ H16, float* __restrict__ attS, float* __restrict__ attD, int n)
{
  __shared__ unsigned short smem[36864];     // 73728 B: [hi 18432][lo 18432]
  int tid = threadIdx.x;
  int wv = tid >> 6, lane = tid & 63;
  int g = lane >> 4, r = lane & 15;
  int rbase = blockIdx.x*64 + wv*16;
  int arow = rbase + r; if (arow >= n) arow = n - 1;

  {
    const uint4* src = (const uint4*)WT;
    uint4* dst = (uint4*)smem;
    #pragma unroll
    for (int i = 0; i < 18; ++i) dst[tid + i*256] = src[tid + i*256];
  }

  bf16x8 Ah[4], Al[4];
  if (SPLITIN){
    const uint4* ph = (const uint4*)(X16 + (size_t)arow*FD);
    #pragma unroll
    for (int kc = 0; kc < 4; ++kc){
      uint4 u = ph[kc*4 + g];
      float2 f0 = __half22float2(__builtin_bit_cast(__half2, u.x));
      float2 f1 = __half22float2(__builtin_bit_cast(__half2, u.y));
      float2 f2 = __half22float2(__builtin_bit_cast(__half2, u.z));
      float2 f3 = __half22float2(__builtin_bit_cast(__half2, u.w));
      float xs[8] = {f0.x,f0.y,f1.x,f1.y,f2.x,f2.y,f3.x,f3.y};
      #pragma unroll
      for (int t = 0; t < 8; ++t){
        unsigned short hh = f2bf(xs[t]);
        Ah[kc][t] = (short)hh;
        Al[kc][t] = (short)f2bf(xs[t] - bf2f(hh));
      }
    }
  } else {
    const float4* px = (const float4*)(Xf + (size_t)arow*FD);
    #pragma unroll
    for (int kc = 0; kc < 4; ++kc){
      float4 x0 = px[(kc*4 + g)*2];
      float4 x1 = px[(kc*4 + g)*2 + 1];
      float xs[8] = {x0.x,x0.y,x0.z,x0.w,x1.x,x1.y,x1.z,x1.w};
      #pragma unroll
      for (int t = 0; t < 8; ++t){
        unsigned short hh = f2bf(xs[t]);
        Ah[kc][t] = (short)hh;
        Al[kc][t] = (short)f2bf(xs[t] - bf2f(hh));
      }
    }
  }

  __syncthreads();

  f32x4 acc[9];
  #pragma unroll
  for (int ct = 0; ct < 9; ++ct) acc[ct] = (f32x4){0.f,0.f,0.f,0.f};

  #pragma unroll
  for (int ct = 0; ct < 9; ++ct){
    int wrow = ct*16 + r;
    int sw = (wrow & 7) << 3;
    #pragma unroll
    for (int kc = 0; kc < 4; ++kc){
      int kidx = (kc*32 + g*8) ^ sw;
      bf16x8 Bh = *(const bf16x8*)&smem[wrow*128 + kidx];
      bf16x8 Bl = *(const bf16x8*)&smem[18432 + wrow*128 + kidx];
      acc[ct] = __builtin_amdgcn_mfma_f32_16x16x32_bf16(Ah[kc], Bh, acc[ct], 0, 0, 0);
      acc[ct] = __builtin_amdgcn_mfma_f32_16x16x32_bf16(Ah[kc], Bl, acc[ct], 0, 0, 0);
      acc[ct] = __builtin_amdgcn_mfma_f32_16x16x32_bf16(Al[kc], Bh, acc[ct], 0, 0, 0);
    }
  }

  #pragma unroll
  for (int j = 0; j < 4; ++j){
    int row = rbase + g*4 + j;
    if (row < n){
      __half2 p0 = __float22half2_rn(make_float2(acc[0][j], acc[1][j]));
      __half2 p1 = __float22half2_rn(make_float2(acc[2][j], acc[3][j]));
      __half2 p2 = __float22half2_rn(make_float2(acc[4][j], acc[5][j]));
      __half2 p3 = __float22half2_rn(make_float2(acc[6][j], acc[7][j]));
      uint4 pk;
      pk.x = __builtin_bit_cast(unsigned, p0);
      pk.y = __builtin_bit_cast(unsigned, p1);
      pk.z = __builtin_bit_cast(unsigned, p2);
      pk.w = __builtin_bit_cast(unsigned, p3);
      H16[(size_t)row*16 + r] = pk;
      if (r < 4)      attS[row*4 + r]       = acc[8][j];
      else if (r < 8) attD[row*4 + (r - 4)] = acc[8][j];
    }
  }
}

// ---------------- per-dst softmax + aggregate (one wave per dst) ----------------
// Round-8 structure (proven 44.5us): 4 edges/iter, 16 lanes/edge, stride-5 stash
// (gcd(5,32)=1 -> conflict-free). No max-subtraction (logits bounded).
// acc[0..3] = ch 4r..4r+3 (head r<8?0:1); acc[4..7] = 64+4r..+3 (head r<8?2:3).
// OUT=0: write packed fp16 H2 rows. OUT=1: fuse bias+lrelu+FC -> out[dst].
template<int OUT>
__global__ __launch_bounds__(256) void agg_kernel(
    const uint2* __restrict__ H16, const float* __restrict__ attS, const float* __restrict__ attD,
    const int* __restrict__ csr, const int* __restrict__ offsets,
    const float* __restrict__ bias, const float* __restrict__ wfc, const float* __restrict__ bfc,
    unsigned* __restrict__ o16, float* __restrict__ out, int n)
{
  __shared__ float lds[4][64*5];
  int wid = (int)((blockIdx.x * (size_t)blockDim.x + threadIdx.x) >> 6);
  int lane = threadIdx.x & 63;
  if (wid >= n) return;
  int g = lane >> 4, r = lane & 15;
  int selA = (r >> 3) & 1;
  float* wl = lds[threadIdx.x >> 6];
  int* wli = (int*)wl;

  int start = offsets[wid], end = offsets[wid+1];
  float4 ad4 = ((const float4*)attD)[wid];

  float z0=0.f, z1=0.f, z2=0.f, z3=0.f;
  float acc[8];
  #pragma unroll
  for (int k = 0; k < 8; ++k) acc[k] = 0.f;

  for (int base2 = start; base2 < end; base2 += 64){
    int cnt = end - base2; if (cnt > 64) cnt = 64;
    float p0,p1,p2,p3; int sb = 0;
    if (lane < cnt){
      int s = csr[base2 + lane];
      sb = s << 5;                    // 32 uint2 per 256B fp16 row
      float4 as4 = ((const float4*)attS)[s];
      p0 = __expf(lrelu(as4.x + ad4.x, 0.2f));
      p1 = __expf(lrelu(as4.y + ad4.y, 0.2f));
      p2 = __expf(lrelu(as4.z + ad4.z, 0.2f));
      p3 = __expf(lrelu(as4.w + ad4.w, 0.2f));
    } else { p0=p1=p2=p3=0.f; }
    z0+=p0; z1+=p1; z2+=p2; z3+=p3;
    wli[lane*5]  = sb;
    wl[lane*5+1] = p0; wl[lane*5+2] = p1; wl[lane*5+3] = p2; wl[lane*5+4] = p3;
    asm volatile("s_waitcnt lgkmcnt(0)" ::: "memory");
    __builtin_amdgcn_sched_barrier(0);
    for (int jj = g; jj < cnt; jj += 4){
      int sbj  = wli[jj*5];
      float pA = wl[jj*5 + 1 + selA];
      float pB = wl[jj*5 + 3 + selA];
      uint2 u0 = H16[(unsigned)(sbj + r)];
      uint2 u1 = H16[(unsigned)(sbj + 16 + r)];
      float2 a0 = __half22float2(__builtin_bit_cast(__half2, u0.x));
      float2 a1 = __half22float2(__builtin_bit_cast(__half2, u0.y));
      float2 a2 = __half22float2(__builtin_bit_cast(__half2, u1.x));
      float2 a3 = __half22float2(__builtin_bit_cast(__half2, u1.y));
      acc[0] += pA*a0.x; acc[1] += pA*a0.y; acc[2] += pA*a1.x; acc[3] += pA*a1.y;
      acc[4] += pB*a2.x; acc[5] += pB*a2.y; acc[6] += pB*a3.x; acc[7] += pB*a3.y;
    }
    __builtin_amdgcn_sched_barrier(0);
  }

  #pragma unroll
  for (int off = 32; off >= 1; off >>= 1){
    z0+=__shfl_xor(z0,off); z1+=__shfl_xor(z1,off);
    z2+=__shfl_xor(z2,off); z3+=__shfl_xor(z3,off);
  }
  #pragma unroll
  for (int k = 0; k < 8; ++k){
    acc[k] += __shfl_xor(acc[k], 16);
    acc[k] += __shfl_xor(acc[k], 32);
  }
  // group g keeps channels ch0 = (g>>1)*64 + 4r + 2*(g&1), ch1 = ch0+1
  float o0 = g==0?acc[0]:g==1?acc[2]:g==2?acc[4]:acc[6];
  float o1 = g==0?acc[1]:g==1?acc[3]:g==2?acc[5]:acc[7];
  int ch0 = ((g>>1)<<6) + (r<<2) + ((g&1)<<1);
  float zz = (g < 2) ? ((r<8)? z0 : z1) : ((r<8)? z2 : z3);
  float inv = 1.f / (zz + 1e-16f);
  float2 b2v = ((const float2*)bias)[ch0 >> 1];
  o0 = lrelu(o0*inv + b2v.x, 0.01f);
  o1 = lrelu(o1*inv + b2v.y, 0.01f);
  if (OUT){
    float2 w2v = ((const float2*)wfc)[ch0 >> 1];
    float t = o0*w2v.x + o1*w2v.y;
    #pragma unroll
    for (int off = 32; off >= 1; off >>= 1) t += __shfl_xor(t, off);
    if (lane == 0) out[wid] = t + bfc[0];
  } else {
    __half2 hv = __float22half2_rn(make_float2(o0, o1));
    o16[(size_t)wid*64 + (ch0 >> 1)] = __builtin_bit_cast(unsigned, hv);
  }
}

extern "C" void kernel_launch(void* const* d_in, const int* in_sizes, int n_in,
                              void* d_out, int out_size, void* d_ws, size_t ws_size,
                              hipStream_t stream)
{
  const float* x   = (const float*)d_in[0];
  const int*   ei  = (const int*)d_in[1];
  const float* W1  = (const float*)d_in[2];
  const float* aS1 = (const float*)d_in[3];
  const float* aD1 = (const float*)d_in[4];
  const float* b1  = (const float*)d_in[5];
  const float* W2  = (const float*)d_in[6];
  const float* aS2 = (const float*)d_in[7];
  const float* aD2 = (const float*)d_in[8];
  const float* b2  = (const float*)d_in[9];
  const float* Wfc = (const float*)d_in[10];
  const float* bfc = (const float*)d_in[11];
  float* out = (float*)d_out;

  int n = in_sizes[0] / FD;
  int E = in_sizes[1] / 2;
  int etot = E + n;
  unsigned rscale = (unsigned)(((8ULL << 32) + n - 1) / (unsigned long long)n);

  char* p = (char*)d_ws;
  auto alloc = [&](size_t bytes)->void*{
    void* r = (void*)p;
    p += (bytes + 255) & ~(size_t)255;
    return r;
  };
  int* counts    = (int*)alloc((size_t)n * 4);
  int* offsets   = (int*)alloc((size_t)(n + 1) * 4);
  int* blocksum  = (int*)alloc(1024 * 4);
  int* csr       = (int*)alloc((size_t)etot * 4);
  float* attS1   = (float*)alloc((size_t)n * 4 * 4);
  float* attD1   = (float*)alloc((size_t)n * 4 * 4);
  float* attS2   = (float*)alloc((size_t)n * 4 * 4);
  float* attD2   = (float*)alloc((size_t)n * 4 * 4);
  unsigned short* WT1 = (unsigned short*)alloc(36864*2);
  unsigned short* WT2 = (unsigned short*)alloc(36864*2);
  uint4* H16     = (uint4*)alloc((size_t)n * FD * 2);
  unsigned short* H2 = (unsigned short*)alloc((size_t)n * FD * 2);

  hipMemsetAsync(counts, 0, (size_t)n * 4, stream);

  const int NB_PART = 512;            // 64 chunks x 8 XCD-filtered block groups
  int nsb = (n + 511) / 512;          // scan blocks (<=128 for n<=65536)
  count_wprep_kernel<<<NB_PART + 144, 256, 0, stream>>>(ei + E, counts, E, rscale,
      NB_PART/8, NB_PART, W1, W2, aS1, aD1, aS2, aD2, WT1, WT2);
  scan1_kernel<<<nsb, 512, 0, stream>>>(counts, offsets, blocksum, n);
  scan3_kernel<<<nsb, 512, 0, stream>>>(counts, offsets, blocksum, csr, n, nsb);
  fill_part_kernel<<<NB_PART, 256, 0, stream>>>(ei, offsets, counts, csr, E, rscale, NB_PART/8);

  int gb = (n + 63) / 64;
  int ab = (int)(((size_t)n * 64 + 255) / 256);

  // layer 1
  gemm_mfma_kernel<0><<<gb, 256, 0, stream>>>(x, nullptr, WT1,
                                              H16, attS1, attD1, n);
  agg_kernel<0><<<ab, 256, 0, stream>>>((const uint2*)H16, attS1, attD1, csr, offsets,
                                        b1, nullptr, nullptr, (unsigned*)H2, nullptr, n);
  // layer 2 (+ fused FC)
  gemm_mfma_kernel<1><<<gb, 256, 0, stream>>>(nullptr, H2, WT2,
                                              H16, attS2, attD2, n);
  agg_kernel<1><<<ab, 256, 0, stream>>>((const uint2*)H16, attS2, attD2, csr, offsets,
                                        b2, Wfc, bfc, nullptr, out, n);
}

// Round 11
// 195.047 us; speedup vs baseline: 1.6388x; 1.0323x over previous
//
#include <hip/hip_runtime.h>
#include <hip/hip_fp16.h>

#define FD 128

typedef __attribute__((ext_vector_type(8))) short bf16x8;
typedef __attribute__((ext_vector_type(4))) float f32x4;

__device__ __forceinline__ float lrelu(float x, float s){ return x > 0.f ? x : s*x; }

__device__ __forceinline__ unsigned short f2bf(float f){
  unsigned u = __builtin_bit_cast(unsigned, f);
  return (unsigned short)((u + 0x7FFFu + ((u >> 16) & 1u)) >> 16);
}
__device__ __forceinline__ float bf2f(unsigned short h){
  unsigned u = ((unsigned)h) << 16;
  return __builtin_bit_cast(float, u);
}

// WT storage (per layer): single ushort buffer, 36864 entries = 73728 B.
//   [0, 18432)     : hi part, XOR-swizzled row-major [144][128]
//   [18432, 36864) : lo part, same layout
// swizzled index for (row w, k): si = w*128 + (k ^ ((w&7)<<3))

// ---------------- count (XCD-partitioned) + wprep fused ----------------
__global__ __launch_bounds__(256) void count_wprep_kernel(const int* __restrict__ dst,
    int* __restrict__ counts, int E, unsigned rscale, int nchunk, int nbc,
    const float* __restrict__ W1, const float* __restrict__ W2,
    const float* __restrict__ aS1, const float* __restrict__ aD1,
    const float* __restrict__ aS2, const float* __restrict__ aD2,
    unsigned short* __restrict__ WT1, unsigned short* __restrict__ WT2)
{
  int b = blockIdx.x;
  if (b < nbc){
    int xcd = b & 7, chunk = b >> 3;
    int nv = E >> 2;
    for (int v = chunk*256 + threadIdx.x; v < nv; v += nchunk*256){
      int4 d4 = ((const int4*)dst)[v];
      #pragma unroll
      for (int t = 0; t < 4; ++t){
        int d = (&d4.x)[t];
        unsigned r = (unsigned)(((unsigned long long)(unsigned)d * rscale) >> 32);
        if ((int)r == xcd) atomicAdd(&counts[d], 1);
      }
    }
    if (chunk == 0 && threadIdx.x < (E & 3)){
      int i = (E & ~3) + threadIdx.x;
      int d = dst[i];
      unsigned r = (unsigned)(((unsigned long long)(unsigned)d * rscale) >> 32);
      if ((int)r == xcd) atomicAdd(&counts[d], 1);
    }
    return;
  }
  int id = (b - nbc)*256 + threadIdx.x;
  if (id < 32768){
    const float* W = (id < 16384) ? W1 : W2;
    unsigned short* T = (id < 16384) ? WT1 : WT2;
    int idx = id & 16383;
    int k = idx >> 7, c = idx & 127;
    int w = ((c & 7) << 4) | (c >> 3);   // channel c -> row w (thread (ct,r) -> ch r*8+ct)
    int si = w*128 + (k ^ ((w & 7) << 3));
    float v = W[idx];
    unsigned short h = f2bf(v);
    T[si] = h;
    T[18432 + si] = f2bf(v - bf2f(h));
  } else if (id < 34816){
    int id2 = id - 32768;
    int layer = id2 >> 10;
    int id3 = id2 & 1023;
    int k = id3 >> 3, cc = id3 & 7;
    const float* W  = layer ? W2 : W1;
    const float* av = (cc < 4) ? (layer ? aS2 : aS1) : (layer ? aD2 : aD1);
    unsigned short* T = layer ? WT2 : WT1;
    int h = cc & 3, base = h*32;
    float acc = 0.f;
    #pragma unroll 8
    for (int c = 0; c < 32; ++c) acc += W[k*FD + base + c] * av[base + c];
    int w = 128 + cc;
    int si = w*128 + (k ^ ((w & 7) << 3));
    unsigned short hh = f2bf(acc);
    T[si] = hh;
    T[18432 + si] = f2bf(acc - bf2f(hh));
  } else if (id < 36864){
    int id2 = id - 34816;
    int layer = id2 >> 10;
    int id3 = id2 & 1023;
    int w = 136 + (id3 >> 7), k = id3 & 127;
    unsigned short* T = layer ? WT2 : WT1;
    int si = w*128 + (k ^ ((w & 7) << 3));
    T[si] = 0;
    T[18432 + si] = 0;
  }
}

// ---------------- multi-block scan of (counts[i]+1), 2 phases ----------------
__global__ __launch_bounds__(512) void scan1_kernel(const int* __restrict__ counts,
    int* __restrict__ offsets, int* __restrict__ blocksum, int n){
  __shared__ int wsum[8];
  int tid = threadIdx.x, lane = tid & 63, wv = tid >> 6;
  int i = blockIdx.x*512 + tid;
  int v = (i < n) ? counts[i] + 1 : 0;
  int incl = v;
  #pragma unroll
  for (int off = 1; off < 64; off <<= 1){
    int t = __shfl_up(incl, off);
    if (lane >= off) incl += t;
  }
  if (lane == 63) wsum[wv] = incl;
  __syncthreads();
  if (wv == 0 && lane < 8){
    int s = wsum[lane];
    #pragma unroll
    for (int off = 1; off < 8; off <<= 1){
      int t = __shfl_up(s, off);
      if (lane >= off) s += t;
    }
    wsum[lane] = s;
  }
  __syncthreads();
  int woff = (wv > 0) ? wsum[wv-1] : 0;
  incl += woff;
  if (i < n) offsets[i] = incl;          // local inclusive
  if (tid == 511) blocksum[blockIdx.x] = incl;
}

// scan3: per-block lookback over blocksum, finalize exclusive global offsets +
// write self-loop csr entries; last element writes offsets[n].
__global__ __launch_bounds__(512) void scan3_kernel(const int* __restrict__ counts,
    int* __restrict__ offsets, const int* __restrict__ blocksum,
    int* __restrict__ csr, int n, int nsb){
  __shared__ int boff_s;
  int tid = threadIdx.x, b = blockIdx.x;
  if (tid < 64){
    int s = 0;
    for (int j = tid; j < b; j += 64) s += blocksum[j];
    #pragma unroll
    for (int off = 32; off >= 1; off >>= 1) s += __shfl_xor(s, off);
    if (tid == 0) boff_s = s;
  }
  __syncthreads();
  int i = b*512 + tid;
  if (i >= n) return;
  int boff = boff_s;
  int v = counts[i] + 1;
  int gl = offsets[i] + boff;
  offsets[i] = gl - v;
  csr[gl - 1] = i;
  if (i == n - 1) offsets[n] = gl;
}

// ---------------- GEMM body: [H(fp16, packed) | attS | attD] ----------------
// 128 rows/block: wave wv computes row groups {b*128+wv*16, b*128+64+wv*16}.
// WT staged in LDS once per block (73.7 KB, shared by 4 waves).
template<int SPLITIN>
__device__ __forceinline__ void gemm_body(int bid, int tid,
    const float* __restrict__ Xf, const unsigned short* __restrict__ X16,
    const unsigned short* __restrict__ WT,
    uint4* __restrict__ H16, float* __restrict__ attS, float* __restrict__ attD,
    int n, unsigned short* smem)
{
  int wv = tid >> 6, lane = tid & 63;
  int g = lane >> 4, r = lane & 15;
  int rb0 = bid*128 + wv*16;

  {
    const uint4* src = (const uint4*)WT;
    uint4* dst = (uint4*)smem;
    #pragma unroll
    for (int i = 0; i < 18; ++i) dst[tid + i*256] = src[tid + i*256];
  }

  bf16x8 Ah[2][4], Al[2][4];
  #pragma unroll
  for (int m = 0; m < 2; ++m){
    int arow = rb0 + m*64 + r; if (arow >= n) arow = n - 1;
    if (SPLITIN){
      const uint4* ph = (const uint4*)(X16 + (size_t)arow*FD);
      #pragma unroll
      for (int kc = 0; kc < 4; ++kc){
        uint4 u = ph[kc*4 + g];
        float2 f0 = __half22float2(__builtin_bit_cast(__half2, u.x));
        float2 f1 = __half22float2(__builtin_bit_cast(__half2, u.y));
        float2 f2 = __half22float2(__builtin_bit_cast(__half2, u.z));
        float2 f3 = __half22float2(__builtin_bit_cast(__half2, u.w));
        float xs[8] = {f0.x,f0.y,f1.x,f1.y,f2.x,f2.y,f3.x,f3.y};
        #pragma unroll
        for (int t = 0; t < 8; ++t){
          unsigned short hh = f2bf(xs[t]);
          Ah[m][kc][t] = (short)hh;
          Al[m][kc][t] = (short)f2bf(xs[t] - bf2f(hh));
        }
      }
    } else {
      const float4* px = (const float4*)(Xf + (size_t)arow*FD);
      #pragma unroll
      for (int kc = 0; kc < 4; ++kc){
        float4 x0 = px[(kc*4 + g)*2];
        float4 x1 = px[(kc*4 + g)*2 + 1];
        float xs[8] = {x0.x,x0.y,x0.z,x0.w,x1.x,x1.y,x1.z,x1.w};
        #pragma unroll
        for (int t = 0; t < 8; ++t){
          unsigned short hh = f2bf(xs[t]);
          Ah[m][kc][t] = (short)hh;
          Al[m][kc][t] = (short)f2bf(xs[t] - bf2f(hh));
        }
      }
    }
  }

  __syncthreads();

  f32x4 acc[2][9];
  #pragma unroll
  for (int m = 0; m < 2; ++m)
    #pragma unroll
    for (int ct = 0; ct < 9; ++ct) acc[m][ct] = (f32x4){0.f,0.f,0.f,0.f};

  #pragma unroll
  for (int ct = 0; ct < 9; ++ct){
    int wrow = ct*16 + r;
    int sw = (wrow & 7) << 3;
    #pragma unroll
    for (int kc = 0; kc < 4; ++kc){
      int kidx = (kc*32 + g*8) ^ sw;
      bf16x8 Bh = *(const bf16x8*)&smem[wrow*128 + kidx];
      bf16x8 Bl = *(const bf16x8*)&smem[18432 + wrow*128 + kidx];
      #pragma unroll
      for (int m = 0; m < 2; ++m){
        acc[m][ct] = __builtin_amdgcn_mfma_f32_16x16x32_bf16(Ah[m][kc], Bh, acc[m][ct], 0, 0, 0);
        acc[m][ct] = __builtin_amdgcn_mfma_f32_16x16x32_bf16(Ah[m][kc], Bl, acc[m][ct], 0, 0, 0);
        acc[m][ct] = __builtin_amdgcn_mfma_f32_16x16x32_bf16(Al[m][kc], Bh, acc[m][ct], 0, 0, 0);
      }
    }
  }

  #pragma unroll
  for (int m = 0; m < 2; ++m){
    #pragma unroll
    for (int j = 0; j < 4; ++j){
      int row = rb0 + m*64 + g*4 + j;
      if (row < n){
        __half2 p0 = __float22half2_rn(make_float2(acc[m][0][j], acc[m][1][j]));
        __half2 p1 = __float22half2_rn(make_float2(acc[m][2][j], acc[m][3][j]));
        __half2 p2 = __float22half2_rn(make_float2(acc[m][4][j], acc[m][5][j]));
        __half2 p3 = __float22half2_rn(make_float2(acc[m][6][j], acc[m][7][j]));
        uint4 pk;
        pk.x = __builtin_bit_cast(unsigned, p0);
        pk.y = __builtin_bit_cast(unsigned, p1);
        pk.z = __builtin_bit_cast(unsigned, p2);
        pk.w = __builtin_bit_cast(unsigned, p3);
        H16[(size_t)row*16 + r] = pk;
        if (r < 4)      attS[row*4 + r]       = acc[m][8][j];
        else if (r < 8) attD[row*4 + (r - 4)] = acc[m][8][j];
      }
    }
  }
}

// ---------------- fused: fill (XCD-partitioned) + layer-1 GEMM ----------------
// Blocks [0,nbf): fill csr slots 0..deg-1 (b&7 XCD mapping preserved).
// Blocks [nbf, nbf+gb): gemm_body<0> on X (f32). The two are independent:
// fill needs scan3's offsets/counts; gemm1 needs only WT1. Overlap hides fill.
__global__ __launch_bounds__(256) void fill_gemm1_kernel(const int* __restrict__ ei,
    const int* __restrict__ offsets, int* __restrict__ counts, int* __restrict__ csr,
    int E, unsigned rscale, int nchunk, int nbf,
    const float* __restrict__ x, const unsigned short* __restrict__ WT1,
    uint4* __restrict__ H16, float* __restrict__ attS1, float* __restrict__ attD1, int n)
{
  __shared__ unsigned short smem[36864];
  int b = blockIdx.x;
  if (b < nbf){
    int xcd = b & 7, chunk = b >> 3;
    int nv = E >> 2;
    for (int v = chunk*256 + threadIdx.x; v < nv; v += nchunk*256){
      int4 s4 = ((const int4*)ei)[v];
      int4 d4 = ((const int4*)(ei + E))[v];
      #pragma unroll
      for (int t = 0; t < 4; ++t){
        int d = (&d4.x)[t];
        unsigned r = (unsigned)(((unsigned long long)(unsigned)d * rscale) >> 32);
        if ((int)r == xcd){
          int c = atomicSub(&counts[d], 1) - 1;
          csr[offsets[d] + c] = (&s4.x)[t];
        }
      }
    }
    if (chunk == 0 && threadIdx.x < (E & 3)){
      int i = (E & ~3) + threadIdx.x;
      int d = ei[E + i];
      unsigned r = (unsigned)(((unsigned long long)(unsigned)d * rscale) >> 32);
      if ((int)r == xcd){
        int c = atomicSub(&counts[d], 1) - 1;
        csr[offsets[d] + c] = ei[i];
      }
    }
  } else {
    gemm_body<0>(b - nbf, threadIdx.x, x, nullptr, WT1, H16, attS1, attD1, n, smem);
  }
}

// layer-2 GEMM (standalone)
__global__ __launch_bounds__(256) void gemm2_kernel(const unsigned short* __restrict__ X16,
    const unsigned short* __restrict__ WT,
    uint4* __restrict__ H16, float* __restrict__ attS, float* __restrict__ attD, int n)
{
  __shared__ unsigned short smem[36864];
  gemm_body<1>(blockIdx.x, threadIdx.x, nullptr, X16, WT, H16, attS, attD, n, smem);
}

// ---------------- per-dst softmax + aggregate (one wave per dst) ----------------
// Round-8 structure (proven 44.5us): 4 edges/iter, 16 lanes/edge, stride-5 stash
// (gcd(5,32)=1 -> conflict-free). No max-subtraction (logits bounded).
// acc[0..3] = ch 4r..4r+3 (head r<8?0:1); acc[4..7] = 64+4r..+3 (head r<8?2:3).
// OUT=0: write packed fp16 H2 rows. OUT=1: fuse bias+lrelu+FC -> out[dst].
template<int OUT>
__global__ __launch_bounds__(256) void agg_kernel(
    const uint2* __restrict__ H16, const float* __restrict__ attS, const float* __restrict__ attD,
    const int* __restrict__ csr, const int* __restrict__ offsets,
    const float* __restrict__ bias, const float* __restrict__ wfc, const float* __restrict__ bfc,
    unsigned* __restrict__ o16, float* __restrict__ out, int n)
{
  __shared__ float lds[4][64*5];
  int wid = (int)((blockIdx.x * (size_t)blockDim.x + threadIdx.x) >> 6);
  int lane = threadIdx.x & 63;
  if (wid >= n) return;
  int g = lane >> 4, r = lane & 15;
  int selA = (r >> 3) & 1;
  float* wl = lds[threadIdx.x >> 6];
  int* wli = (int*)wl;

  int start = offsets[wid], end = offsets[wid+1];
  float4 ad4 = ((const float4*)attD)[wid];

  float z0=0.f, z1=0.f, z2=0.f, z3=0.f;
  float acc[8];
  #pragma unroll
  for (int k = 0; k < 8; ++k) acc[k] = 0.f;

  for (int base2 = start; base2 < end; base2 += 64){
    int cnt = end - base2; if (cnt > 64) cnt = 64;
    float p0,p1,p2,p3; int sb = 0;
    if (lane < cnt){
      int s = csr[base2 + lane];
      sb = s << 5;                    // 32 uint2 per 256B fp16 row
      float4 as4 = ((const float4*)attS)[s];
      p0 = __expf(lrelu(as4.x + ad4.x, 0.2f));
      p1 = __expf(lrelu(as4.y + ad4.y, 0.2f));
      p2 = __expf(lrelu(as4.z + ad4.z, 0.2f));
      p3 = __expf(lrelu(as4.w + ad4.w, 0.2f));
    } else { p0=p1=p2=p3=0.f; }
    z0+=p0; z1+=p1; z2+=p2; z3+=p3;
    wli[lane*5]  = sb;
    wl[lane*5+1] = p0; wl[lane*5+2] = p1; wl[lane*5+3] = p2; wl[lane*5+4] = p3;
    asm volatile("s_waitcnt lgkmcnt(0)" ::: "memory");
    __builtin_amdgcn_sched_barrier(0);
    for (int jj = g; jj < cnt; jj += 4){
      int sbj  = wli[jj*5];
      float pA = wl[jj*5 + 1 + selA];
      float pB = wl[jj*5 + 3 + selA];
      uint2 u0 = H16[(unsigned)(sbj + r)];
      uint2 u1 = H16[(unsigned)(sbj + 16 + r)];
      float2 a0 = __half22float2(__builtin_bit_cast(__half2, u0.x));
      float2 a1 = __half22float2(__builtin_bit_cast(__half2, u0.y));
      float2 a2 = __half22float2(__builtin_bit_cast(__half2, u1.x));
      float2 a3 = __half22float2(__builtin_bit_cast(__half2, u1.y));
      acc[0] += pA*a0.x; acc[1] += pA*a0.y; acc[2] += pA*a1.x; acc[3] += pA*a1.y;
      acc[4] += pB*a2.x; acc[5] += pB*a2.y; acc[6] += pB*a3.x; acc[7] += pB*a3.y;
    }
    __builtin_amdgcn_sched_barrier(0);
  }

  #pragma unroll
  for (int off = 32; off >= 1; off >>= 1){
    z0+=__shfl_xor(z0,off); z1+=__shfl_xor(z1,off);
    z2+=__shfl_xor(z2,off); z3+=__shfl_xor(z3,off);
  }
  #pragma unroll
  for (int k = 0; k < 8; ++k){
    acc[k] += __shfl_xor(acc[k], 16);
    acc[k] += __shfl_xor(acc[k], 32);
  }
  // group g keeps channels ch0 = (g>>1)*64 + 4r + 2*(g&1), ch1 = ch0+1
  float o0 = g==0?acc[0]:g==1?acc[2]:g==2?acc[4]:acc[6];
  float o1 = g==0?acc[1]:g==1?acc[3]:g==2?acc[5]:acc[7];
  int ch0 = ((g>>1)<<6) + (r<<2) + ((g&1)<<1);
  float zz = (g < 2) ? ((r<8)? z0 : z1) : ((r<8)? z2 : z3);
  float inv = 1.f / (zz + 1e-16f);
  float2 b2v = ((const float2*)bias)[ch0 >> 1];
  o0 = lrelu(o0*inv + b2v.x, 0.01f);
  o1 = lrelu(o1*inv + b2v.y, 0.01f);
  if (OUT){
    float2 w2v = ((const float2*)wfc)[ch0 >> 1];
    float t = o0*w2v.x + o1*w2v.y;
    #pragma unroll
    for (int off = 32; off >= 1; off >>= 1) t += __shfl_xor(t, off);
    if (lane == 0) out[wid] = t + bfc[0];
  } else {
    __half2 hv = __float22half2_rn(make_float2(o0, o1));
    o16[(size_t)wid*64 + (ch0 >> 1)] = __builtin_bit_cast(unsigned, hv);
  }
}

extern "C" void kernel_launch(void* const* d_in, const int* in_sizes, int n_in,
                              void* d_out, int out_size, void* d_ws, size_t ws_size,
                              hipStream_t stream)
{
  const float* x   = (const float*)d_in[0];
  const int*   ei  = (const int*)d_in[1];
  const float* W1  = (const float*)d_in[2];
  const float* aS1 = (const float*)d_in[3];
  const float* aD1 = (const float*)d_in[4];
  const float* b1  = (const float*)d_in[5];
  const float* W2  = (const float*)d_in[6];
  const float* aS2 = (const float*)d_in[7];
  const float* aD2 = (const float*)d_in[8];
  const float* b2  = (const float*)d_in[9];
  const float* Wfc = (const float*)d_in[10];
  const float* bfc = (const float*)d_in[11];
  float* out = (float*)d_out;

  int n = in_sizes[0] / FD;
  int E = in_sizes[1] / 2;
  int etot = E + n;
  unsigned rscale = (unsigned)(((8ULL << 32) + n - 1) / (unsigned long long)n);

  char* p = (char*)d_ws;
  auto alloc = [&](size_t bytes)->void*{
    void* r = (void*)p;
    p += (bytes + 255) & ~(size_t)255;
    return r;
  };
  int* counts    = (int*)alloc((size_t)n * 4);
  int* offsets   = (int*)alloc((size_t)(n + 1) * 4);
  int* blocksum  = (int*)alloc(1024 * 4);
  int* csr       = (int*)alloc((size_t)etot * 4);
  float* attS1   = (float*)alloc((size_t)n * 4 * 4);
  float* attD1   = (float*)alloc((size_t)n * 4 * 4);
  float* attS2   = (float*)alloc((size_t)n * 4 * 4);
  float* attD2   = (float*)alloc((size_t)n * 4 * 4);
  unsigned short* WT1 = (unsigned short*)alloc(36864*2);
  unsigned short* WT2 = (unsigned short*)alloc(36864*2);
  uint4* H16     = (uint4*)alloc((size_t)n * FD * 2);
  unsigned short* H2 = (unsigned short*)alloc((size_t)n * FD * 2);

  hipMemsetAsync(counts, 0, (size_t)n * 4, stream);

  const int NB_PART = 512;            // 64 chunks x 8 XCD-filtered block groups
  int nsb = (n + 511) / 512;          // scan blocks (<=128 for n<=65536)
  int gb  = (n + 127) / 128;          // gemm blocks (128 rows each)

  count_wprep_kernel<<<NB_PART + 144, 256, 0, stream>>>(ei + E, counts, E, rscale,
      NB_PART/8, NB_PART, W1, W2, aS1, aD1, aS2, aD2, WT1, WT2);
  scan1_kernel<<<nsb, 512, 0, stream>>>(counts, offsets, blocksum, n);
  scan3_kernel<<<nsb, 512, 0, stream>>>(counts, offsets, blocksum, csr, n, nsb);

  // fused: fill (blocks [0,512)) + layer-1 gemm (blocks [512, 512+gb))
  fill_gemm1_kernel<<<NB_PART + gb, 256, 0, stream>>>(ei, offsets, counts, csr,
      E, rscale, NB_PART/8, NB_PART, x, WT1, H16, attS1, attD1, n);

  int ab = (int)(((size_t)n * 64 + 255) / 256);
  agg_kernel<0><<<ab, 256, 0, stream>>>((const uint2*)H16, attS1, attD1, csr, offsets,
                                        b1, nullptr, nullptr, (unsigned*)H2, nullptr, n);
  gemm2_kernel<<<gb, 256, 0, stream>>>(H2, WT2, H16, attS2, attD2, n);
  agg_kernel<1><<<ab, 256, 0, stream>>>((const uint2*)H16, attS2, attD2, csr, offsets,
                                        b2, Wfc, bfc, nullptr, out, n);
}